// Round 3
// baseline (452.769 us; speedup 1.0000x reference)
//
#include <hip/hip_runtime.h>

// LogitSelector: per-row top-100 (ascending), label position, miss→replace col 0.
// Reference: jax.lax.top_k (ties: lower index first), reversed; take_along_axis; argmax.

#define NROWS 8192
#define NCOLS 6714
#define K 100
#define NBINS 2048      // top 11 bits of order-flipped float
#define CAP 512         // candidate capacity (expected ~150 for N(0,1) data)
#define BLK 256

__global__ __launch_bounds__(BLK) void logit_selector_kernel(
    const float* __restrict__ out_mat,
    const int*   __restrict__ labels,
    float*       __restrict__ new_out,   // [NROWS][K]
    float*       __restrict__ new_lab)   // [NROWS] written as float
{
    __shared__ float        rowv[NCOLS];        // 26856 B
    __shared__ unsigned int hist[NBINS];        //  8192 B
    __shared__ unsigned int chunk[64];          //   256 B (64 chunks x 32 bins)
    __shared__ float        cval[CAP];          //  2048 B
    __shared__ int          cidx[CAP];          //  2048 B
    __shared__ unsigned int s_cnum;
    __shared__ int          s_bin;
    __shared__ int          s_lab;
    __shared__ int          s_has;

    const int row = blockIdx.x;
    const int tid = threadIdx.x;
    const float* __restrict__ rp = out_mat + (size_t)row * NCOLS;

    for (int b = tid; b < NBINS; b += BLK) hist[b] = 0;
    if (tid == 0) { s_cnum = 0; s_has = 0; s_lab = 0; }
    __syncthreads();

    // Pass 1: coalesced load -> LDS row + histogram of order-preserving key.
    for (int i = tid; i < NCOLS; i += BLK) {
        float v = rp[i];
        rowv[i] = v;
        unsigned int b   = __float_as_uint(v);
        unsigned int key = ((int)b < 0) ? ~b : (b | 0x80000000u);
        atomicAdd(&hist[key >> 21], 1u);
    }
    __syncthreads();

    // Chunk sums: 64 chunks of 32 bins.
    if (tid < 64) {
        unsigned int cs = 0;
        #pragma unroll
        for (int j = 0; j < 32; ++j) cs += hist[tid * 32 + j];
        chunk[tid] = cs;
    }
    __syncthreads();

    // Find bin B containing the K-th largest (scan from top).
    if (tid == 0) {
        unsigned int cum = 0;
        int B = 0;
        for (int c = 63; c >= 0; --c) {
            if (cum + chunk[c] >= (unsigned)K) {
                for (int b = c * 32 + 31; b >= c * 32; --b) {
                    if (cum + hist[b] >= (unsigned)K) { B = b; break; }
                    cum += hist[b];
                }
                break;
            }
            cum += chunk[c];
        }
        s_bin = B;
    }
    __syncthreads();

    // Pass 2: collect candidates (all elements in bins >= B) from LDS.
    const unsigned int B = (unsigned int)s_bin;
    for (int i = tid; i < NCOLS; i += BLK) {
        float v = rowv[i];
        unsigned int b   = __float_as_uint(v);
        unsigned int key = ((int)b < 0) ? ~b : (b | 0x80000000u);
        if ((key >> 21) >= B) {
            unsigned int p = atomicAdd(&s_cnum, 1u);
            if (p < CAP) { cval[p] = v; cidx[p] = i; }
        }
    }
    __syncthreads();

    const int C = (int)min(s_cnum, (unsigned int)CAP);
    const int label = labels[row];

    // Exact ranking: rank = #candidates that beat me under (val desc, idx asc).
    // Ranks are a bijection onto [0, C); rank k < K -> output column (K-1)-k.
    for (int j = tid; j < C; j += BLK) {
        const float vj = cval[j];
        const int   ij = cidx[j];
        int rank = 0;
        for (int c = 0; c < C; ++c) {
            const float vc = cval[c];
            rank += (vc > vj) || ((vc == vj) && (cidx[c] < ij));
        }
        if (rank < K) {
            const int col = (K - 1) - rank;
            new_out[(size_t)row * K + col] = vj;
            if (ij == label) { s_has = 1; s_lab = col; }
        }
    }
    __syncthreads();

    if (tid == 0) {
        int lab = s_lab;
        if (!s_has) {                       // label missed top-K: replace col 0
            new_out[(size_t)row * K] = rowv[label];
            lab = 0;
        }
        new_lab[row] = (float)lab;
    }
}

extern "C" void kernel_launch(void* const* d_in, const int* in_sizes, int n_in,
                              void* d_out, int out_size, void* d_ws, size_t ws_size,
                              hipStream_t stream) {
    const float* out_mat = (const float*)d_in[0];
    const int*   labels  = (const int*)d_in[1];
    float* new_out = (float*)d_out;                  // 8192*100 floats
    float* new_lab = (float*)d_out + (size_t)NROWS * K;  // 8192 floats

    logit_selector_kernel<<<dim3(NROWS), dim3(BLK), 0, stream>>>(
        out_mat, labels, new_out, new_lab);
}

// Round 4
// 330.165 us; speedup vs baseline: 1.3713x; 1.3713x over previous
//
#include <hip/hip_runtime.h>

// LogitSelector: per-row top-100 (ascending), label position, miss→replace col 0.
// Reference: jax.lax.top_k (ties: lower index first), reversed; take_along_axis; argmax.
//
// Strategy: speculative-threshold candidate filter (t=1.9 for N(0,1) data gives
// ~193 candidates/row, always in [K, CAP]), then exact O(C^2) rank among
// candidates. Bisection fallback keeps it correct for arbitrary data.
// No histogram, no row LDS buffer, no serial scans -> 4.2 KB LDS, 8 blocks/CU.

#define NROWS 8192
#define NCOLS 6714
#define NC2   3357     // NCOLS/2 exact; every row is 8B-aligned (26856 % 8 == 0)
#define K     100
#define CAP   512
#define BLK   256

__global__ __launch_bounds__(BLK) void logit_selector_kernel(
    const float* __restrict__ out_mat,
    const int*   __restrict__ labels,
    float*       __restrict__ new_out,   // [NROWS][K]
    float*       __restrict__ new_lab)   // [NROWS] written as float
{
    __shared__ float        cval[CAP];
    __shared__ int          cidx[CAP];
    __shared__ unsigned int s_cnum;
    __shared__ int          s_lab;
    __shared__ int          s_has;

    const int row = blockIdx.x;
    const int tid = threadIdx.x;
    const float*  __restrict__ rp  = out_mat + (size_t)row * NCOLS;
    const float2* __restrict__ rp2 = (const float2*)rp;

    if (tid == 0) { s_has = 0; s_lab = 0; }

    // --- Candidate collection with speculative threshold (+ bisection fallback).
    // Normal case: exactly one pass at t=1.9.
    float lo = -50.0f, hi = 50.0f;
    float t  = 1.9f;
    unsigned int cnt;
    for (int attempt = 0; ; ++attempt) {
        if (tid == 0) s_cnum = 0;
        __syncthreads();

        #pragma unroll 4
        for (int i = tid; i < NC2; i += BLK) {
            float2 v2 = rp2[i];
            if (v2.x > t) {
                unsigned int p = atomicAdd(&s_cnum, 1u);
                if (p < CAP) { cval[p] = v2.x; cidx[p] = 2 * i; }
            }
            if (v2.y > t) {
                unsigned int p = atomicAdd(&s_cnum, 1u);
                if (p < CAP) { cval[p] = v2.y; cidx[p] = 2 * i + 1; }
            }
        }
        __syncthreads();
        cnt = s_cnum;                       // uniform across block
        if ((cnt >= K && cnt <= CAP) || attempt >= 62) break;
        if (cnt < (unsigned int)K) hi = t; else lo = t;
        t = 0.5f * (lo + hi);
        __syncthreads();                    // protect s_cnum reset vs. cnt reads
    }

    const int C = (int)min(cnt, (unsigned int)CAP);
    const int label = labels[row];

    // --- Exact ranking: rank = #candidates beating me under (val desc, idx asc).
    // Ranks are a bijection onto [0, C); rank k < K -> output column (K-1)-k.
    for (int j = tid; j < C; j += BLK) {
        const float vj = cval[j];
        const int   ij = cidx[j];
        int rank = 0;
        for (int c = 0; c < C; ++c) {
            const float vc = cval[c];
            rank += (vc > vj) || ((vc == vj) && (cidx[c] < ij));
        }
        if (rank < K) {
            const int col = (K - 1) - rank;
            new_out[(size_t)row * K + col] = vj;
            if (ij == label) { s_has = 1; s_lab = col; }
        }
    }
    __syncthreads();

    if (tid == 0) {
        int lab = s_lab;
        if (!s_has) {                       // label missed top-K: replace col 0
            new_out[(size_t)row * K] = rp[label];
            lab = 0;
        }
        new_lab[row] = (float)lab;
    }
}

extern "C" void kernel_launch(void* const* d_in, const int* in_sizes, int n_in,
                              void* d_out, int out_size, void* d_ws, size_t ws_size,
                              hipStream_t stream) {
    const float* out_mat = (const float*)d_in[0];
    const int*   labels  = (const int*)d_in[1];
    float* new_out = (float*)d_out;                      // 8192*100 floats
    float* new_lab = (float*)d_out + (size_t)NROWS * K;  // 8192 floats

    logit_selector_kernel<<<dim3(NROWS), dim3(BLK), 0, stream>>>(
        out_mat, labels, new_out, new_lab);
}